// Round 5
// baseline (556.680 us; speedup 1.0000x reference)
//
#include <hip/hip_runtime.h>
#include <math.h>

// Problem constants (from reference setup_inputs)
#define B_    2
#define LA_   512
#define LB_   512
#define DH_   1024
#define P_    64
#define NCH_  257          // 4*P + 1
#define EPS_  1e-8f
#define CH_   ((size_t)LA_ * LB_)   // elements per channel plane (262144)

// map_kernel geometry: 256 sim blocks first (co-resident from t=0, no tail),
// then 2048 writer blocks: one per (plane, quarter) — each writes a
// contiguous 256 KB span, blocks ordered linearly over the output.
#define SIMBLK_  256
#define WQ_      4                  // quarters per plane
#define QROWS_   (LA_ / WQ_)        // 128 rows per writer block

// ---------------------------------------------------------------------------
// Kernel 1: z = gelu_exact(h @ W + b), stored TRANSPOSED [b, p, i];
// rn = 1/sqrt(sum_p z^2 + EPS). One block per row; blocks 0..1023 = side A,
// 1024..2047 = side B. 256 threads.  (unchanged — verified)
// ---------------------------------------------------------------------------
__global__ __launch_bounds__(256) void proj_gelu_kernel(
    const float* __restrict__ h_a, const float* __restrict__ Wa,
    const float* __restrict__ ba,
    const float* __restrict__ h_b, const float* __restrict__ Wb,
    const float* __restrict__ bb,
    float* __restrict__ zat,   // [B, P, LA]
    float* __restrict__ zbt,   // [B, P, LB]
    float* __restrict__ rna,   // [B*LA]
    float* __restrict__ rnb)   // [B*LB]
{
    __shared__ __align__(16) float hs[DH_];
    __shared__ __align__(16) float partial[256 * 4];   // [q][p] = [16][64]

    const int side = blockIdx.x >> 10;      // 0 = A, 1 = B
    const int row  = blockIdx.x & 1023;     // b*512 + i
    const int b    = row >> 9;
    const int i    = row & 511;
    const int tid  = threadIdx.x;

    const float* h    = side ? h_b : h_a;
    const float* W    = side ? Wb  : Wa;
    const float* bias = side ? bb  : ba;
    float* z  = side ? zbt : zat;
    float* rn = side ? rnb : rna;

    // Stage the h row (4 KB) into LDS, 256 threads x float4
    ((float4*)hs)[tid] = ((const float4*)(h + (size_t)row * DH_))[tid];
    __syncthreads();

    // thread t: channels p = pg..pg+3, k-chunk q (64 wide)
    const int pg = (tid & 15) * 4;
    const int q  = tid >> 4;                // 0..15
    const float* Wq = W + (size_t)(q * 64) * P_ + pg;
    float4 acc = make_float4(0.f, 0.f, 0.f, 0.f);
    #pragma unroll 8
    for (int k = 0; k < 64; ++k) {
        const float  hv = hs[q * 64 + k];
        const float4 w  = *(const float4*)(Wq + (size_t)k * P_);
        acc.x = fmaf(hv, w.x, acc.x);
        acc.y = fmaf(hv, w.y, acc.y);
        acc.z = fmaf(hv, w.z, acc.z);
        acc.w = fmaf(hv, w.w, acc.w);
    }
    *(float4*)(partial + tid * 4) = acc;
    __syncthreads();

    if (tid < 64) {
        float v = partial[tid];                       // q = 0
        #pragma unroll
        for (int qq = 1; qq < 16; ++qq)
            v += partial[qq * 64 + tid];              // conflict-free: stride 64
        v += bias[tid];
        // exact GELU: 0.5*x*(1+erf(x/sqrt(2)))
        float g = 0.5f * v * (1.f + erff(v * 0.70710678118654752f));

        z[((size_t)(b * P_ + tid)) * 512 + i] = g;   // transposed store

        float s = g * g;
        #pragma unroll
        for (int off = 32; off > 0; off >>= 1)
            s += __shfl_down(s, off, 64);
        if (tid == 0)
            rn[row] = 1.f / sqrtf(s + EPS_);
    }
}

// ---------------------------------------------------------------------------
// Kernel 2: staged writer + sim (union of round-2 / round-4 good pieces).
//   bid <  256 : sim plane block (16x128 strip; verified math, co-resident
//                from t=0 so no serialized tail).
//   bid >= 256 : writer. w = bid-256 in [0,2048): plane = w>>2 (linear plane
//     order -> fill-shaped DRAM walk at 256 KB granularity), quarter = w&3.
//     Operands staged ONCE per block: zbv (thread's float4 of the zb row) in
//     REGISTERS, za column in LDS (per-iteration read is wave-uniform ->
//     broadcast on the LDS pipe, leaving the TA/L1 vector-memory pipe for
//     stores only). t==1 planes need no za: pure-store loop at fill rate.
// ---------------------------------------------------------------------------
__global__ __launch_bounds__(256) void map_kernel(
    const float* __restrict__ zat,   // [B, P, LA]
    const float* __restrict__ zbt,   // [B, P, LB]
    const float* __restrict__ rna,
    const float* __restrict__ rnb,
    float* __restrict__ out)         // [B, 257, LA, LB]
{
    const int tid = threadIdx.x;
    const int bid = blockIdx.x;

    if (bid >= SIMBLK_) {
        // --------------------- staged linear writer ---------------------
        __shared__ __align__(16) float zacol[QROWS_];   // 512 B

        const int w       = bid - SIMBLK_;   // 0..2047
        const int plane   = w >> 2;          // 0..511  (linear over output)
        const int quarter = w & 3;
        const int b       = plane >> 8;
        const int ch      = plane & 255;
        const int t       = ch >> 6;
        const int p       = ch & 63;
        const int i0      = quarter * QROWS_;

        const size_t zoff = ((size_t)(b * P_ + p)) << 9;   // (b*64+p)*512

        // zb: thread's own float4, directly to register (L2 hit; pairs of
        // threads share an address -> broadcast). za column -> LDS.
        const int jj = (tid & 127) * 4;
        const float4 zbv = *(const float4*)(zbt + zoff + jj);
        if (tid < 32)
            ((float4*)zacol)[tid] = ((const float4*)(zat + zoff + i0))[tid];
        __syncthreads();

        const int half = tid >> 7;           // row parity within pair
        float* op = out + (((size_t)(b * NCH_ + ch)) << 18)
                        + (size_t)(i0 + half) * LB_ + jj;

        if (t == 1) {                        // out[i][j] = zb[j] — pure stores
            #pragma unroll 8
            for (int it = 0; it < QROWS_ / 2; ++it) {
                *(float4*)op = zbv;
                op += 2 * LB_;
            }
        } else if (t == 0) {                 // out[i][j] = za[i]
            #pragma unroll 8
            for (int it = 0; it < QROWS_ / 2; ++it) {
                const float a = zacol[2 * it + half];   // wave-uniform ds_read
                *(float4*)op = make_float4(a, a, a, a);
                op += 2 * LB_;
            }
        } else if (t == 2) {                 // |za - zb|
            #pragma unroll 8
            for (int it = 0; it < QROWS_ / 2; ++it) {
                const float a = zacol[2 * it + half];
                *(float4*)op = make_float4(fabsf(a - zbv.x), fabsf(a - zbv.y),
                                           fabsf(a - zbv.z), fabsf(a - zbv.w));
                op += 2 * LB_;
            }
        } else {                             // za * zb
            #pragma unroll 8
            for (int it = 0; it < QROWS_ / 2; ++it) {
                const float a = zacol[2 * it + half];
                *(float4*)op = make_float4(a * zbv.x, a * zbv.y,
                                           a * zbv.z, a * zbv.w);
                op += 2 * LB_;
            }
        }
    } else {
        // ------------------------- sim plane -------------------------
        // bid in [0,256): b = bid>>7, r = bid&127 -> i0 = (r>>2)*16,
        // j0 = (r&3)*128.  (verified math, unchanged)
        __shared__ __align__(16) float zas[P_ * 16];   // [p][ii] 4 KB

        const int s  = bid;
        const int b  = s >> 7;
        const int r  = s & 127;
        const int i0 = (r >> 2) * 16;
        const int j0 = (r & 3) * 128;

        {   // stage za strip: thread -> (p = tid>>2, ii = (tid&3)*4)
            const int p  = tid >> 2;
            const int i4 = (tid & 3) * 4;
            *(float4*)(zas + p * 16 + i4) =
                *(const float4*)(zat + (size_t)(b * P_ + p) * 512 + i0 + i4);
        }
        __syncthreads();

        const int rr = tid >> 7;             // row-half: rows rr*8 .. rr*8+7
        const int j  = j0 + (tid & 127);

        float acc[8];
        #pragma unroll
        for (int u = 0; u < 8; ++u) acc[u] = 0.f;

        for (int p = 0; p < P_; ++p) {
            const float zb = zbt[(size_t)(b * P_ + p) * 512 + j];
            #pragma unroll
            for (int u = 0; u < 8; ++u)
                acc[u] = fmaf(zas[p * 16 + rr * 8 + u], zb, acc[u]);
        }

        const float rbj = rnb[b * 512 + j];
        float* plane = out + (size_t)(b * NCH_ + 256) * CH_;
        #pragma unroll
        for (int u = 0; u < 8; ++u) {
            const int i = i0 + rr * 8 + u;
            plane[(size_t)i * LB_ + j] = acc[u] * rna[b * 512 + i] * rbj;
        }
    }
}

// ---------------------------------------------------------------------------
extern "C" void kernel_launch(void* const* d_in, const int* in_sizes, int n_in,
                              void* d_out, int out_size, void* d_ws, size_t ws_size,
                              hipStream_t stream)
{
    const float* h_a = (const float*)d_in[0];
    const float* h_b = (const float*)d_in[1];
    const float* Wa  = (const float*)d_in[2];
    const float* ba  = (const float*)d_in[3];
    const float* Wb  = (const float*)d_in[4];
    const float* bb  = (const float*)d_in[5];
    float* out = (float*)d_out;

    // workspace (floats): zat[65536] | zbt[65536] | rna[1024] | rnb[1024]
    float* ws  = (float*)d_ws;
    float* zat = ws;
    float* zbt = zat + (size_t)B_ * P_ * LA_;
    float* rna = zbt + (size_t)B_ * P_ * LB_;
    float* rnb = rna + (size_t)B_ * LA_;

    proj_gelu_kernel<<<2 * B_ * LA_, 256, 0, stream>>>(
        h_a, Wa, ba, h_b, Wb, bb, zat, zbt, rna, rnb);
    map_kernel<<<dim3(SIMBLK_ + B_ * 256 * WQ_), 256, 0, stream>>>(
        zat, zbt, rna, rnb, out);
}

// Round 6
// 545.141 us; speedup vs baseline: 1.0212x; 1.0212x over previous
//
#include <hip/hip_runtime.h>
#include <math.h>

// Problem constants (from reference setup_inputs)
#define B_    2
#define LA_   512
#define LB_   512
#define DH_   1024
#define P_    64
#define NCH_  257          // 4*P + 1
#define EPS_  1e-8f
#define CH_   ((size_t)LA_ * LB_)   // elements per channel plane (262144)

// map_kernel geometry: 256 sim blocks first (co-resident from t=0, no tail),
// then 1792 grid-stride writer blocks covering the 512 broadcast planes.
#define SIMBLK_  256
#define WBLK_    1792
#define NQ_      ((size_t)512 * CH_ / 4)          // 33,554,432 float4 stores
#define WSTRIDE_ ((size_t)WBLK_ * 256)            // 458,752 threads

// ---------------------------------------------------------------------------
// Kernel 1: z = gelu_exact(h @ W + b), stored TRANSPOSED [b, p, i];
// rn = 1/sqrt(sum_p z^2 + EPS). One block per row; blocks 0..1023 = side A,
// 1024..2047 = side B. 256 threads.  (verified)
// ---------------------------------------------------------------------------
__global__ __launch_bounds__(256) void proj_gelu_kernel(
    const float* __restrict__ h_a, const float* __restrict__ Wa,
    const float* __restrict__ ba,
    const float* __restrict__ h_b, const float* __restrict__ Wb,
    const float* __restrict__ bb,
    float* __restrict__ zat,   // [B, P, LA]
    float* __restrict__ zbt,   // [B, P, LB]
    float* __restrict__ rna,   // [B*LA]
    float* __restrict__ rnb)   // [B*LB]
{
    __shared__ __align__(16) float hs[DH_];
    __shared__ __align__(16) float partial[256 * 4];   // [q][p] = [16][64]

    const int side = blockIdx.x >> 10;      // 0 = A, 1 = B
    const int row  = blockIdx.x & 1023;     // b*512 + i
    const int b    = row >> 9;
    const int i    = row & 511;
    const int tid  = threadIdx.x;

    const float* h    = side ? h_b : h_a;
    const float* W    = side ? Wb  : Wa;
    const float* bias = side ? bb  : ba;
    float* z  = side ? zbt : zat;
    float* rn = side ? rnb : rna;

    // Stage the h row (4 KB) into LDS, 256 threads x float4
    ((float4*)hs)[tid] = ((const float4*)(h + (size_t)row * DH_))[tid];
    __syncthreads();

    // thread t: channels p = pg..pg+3, k-chunk q (64 wide)
    const int pg = (tid & 15) * 4;
    const int q  = tid >> 4;                // 0..15
    const float* Wq = W + (size_t)(q * 64) * P_ + pg;
    float4 acc = make_float4(0.f, 0.f, 0.f, 0.f);
    #pragma unroll 8
    for (int k = 0; k < 64; ++k) {
        const float  hv = hs[q * 64 + k];
        const float4 w  = *(const float4*)(Wq + (size_t)k * P_);
        acc.x = fmaf(hv, w.x, acc.x);
        acc.y = fmaf(hv, w.y, acc.y);
        acc.z = fmaf(hv, w.z, acc.z);
        acc.w = fmaf(hv, w.w, acc.w);
    }
    *(float4*)(partial + tid * 4) = acc;
    __syncthreads();

    if (tid < 64) {
        float v = partial[tid];                       // q = 0
        #pragma unroll
        for (int qq = 1; qq < 16; ++qq)
            v += partial[qq * 64 + tid];              // conflict-free: stride 64
        v += bias[tid];
        // exact GELU: 0.5*x*(1+erf(x/sqrt(2)))
        float g = 0.5f * v * (1.f + erff(v * 0.70710678118654752f));

        z[((size_t)(b * P_ + tid)) * 512 + i] = g;   // transposed store

        float s = g * g;
        #pragma unroll
        for (int off = 32; off > 0; off >>= 1)
            s += __shfl_down(s, off, 64);
        if (tid == 0)
            rn[row] = 1.f / sqrtf(s + EPS_);
    }
}

// ---------------------------------------------------------------------------
// Kernel 2: FILL-SHAPED writer + sim (round-4 configuration — best measured).
//   bid <  256 : sim plane block (16-row x 128-col strip).
//   bid >= 256 : grid-stride LINEAR writer over the 512 broadcast planes —
//     the exact memory-walk of fillBufferAligned. float4 per thread per
//     iteration; decode is pure shifts/ands. Per wave: plane & i uniform,
//     za broadcast L2 load, zb 1 KB contiguous L2 load, branch uniform.
//     (A/B across r2/r4/r5 showed this linear store stream beats both
//     staged/tiled variants by ~10 us — store address order dominates.)
// ---------------------------------------------------------------------------
__global__ __launch_bounds__(256) void map_kernel(
    const float* __restrict__ zat,   // [B, P, LA]
    const float* __restrict__ zbt,   // [B, P, LB]
    const float* __restrict__ rna,
    const float* __restrict__ rnb,
    float* __restrict__ out)         // [B, 257, LA, LB]
{
    const int tid = threadIdx.x;
    const int bid = blockIdx.x;

    if (bid >= SIMBLK_) {
        // ------------------ linear grid-stride writer ------------------
        const int wid = bid - SIMBLK_;
        size_t q = (size_t)wid * 256 + tid;
        #pragma unroll 2
        for (; q < NQ_; q += WSTRIDE_) {
            const int plane = (int)(q >> 16);        // 0..511
            const int b     = plane >> 8;
            const int ch    = plane & 255;
            const int t     = ch >> 6;
            const int p     = ch & 63;
            const int w4    = (int)(q & 65535);      // float4 index in plane
            const int i     = w4 >> 7;
            const int j     = (w4 & 127) << 2;

            const size_t zoff = ((size_t)((b << 6) + p)) << 9;  // (b*64+p)*512
            const float  a    = zat[zoff + i];
            const float4 zb   = *(const float4*)(zbt + zoff + j);

            float4 v;
            if (t == 0)       v = make_float4(a, a, a, a);
            else if (t == 1)  v = zb;
            else if (t == 2)  v = make_float4(fabsf(a - zb.x), fabsf(a - zb.y),
                                              fabsf(a - zb.z), fabsf(a - zb.w));
            else              v = make_float4(a * zb.x, a * zb.y,
                                              a * zb.z, a * zb.w);

            float* op = out + (((size_t)(b * NCH_ + ch)) << 18) + ((size_t)w4 << 2);
            *(float4*)op = v;
        }
    } else {
        // ------------------------- sim plane -------------------------
        // bid in [0,256): b = bid>>7, r = bid&127 -> i0 = (r>>2)*16,
        // j0 = (r&3)*128.  (verified math)
        __shared__ __align__(16) float zas[P_ * 16];   // [p][ii] 4 KB

        const int s  = bid;
        const int b  = s >> 7;
        const int r  = s & 127;
        const int i0 = (r >> 2) * 16;
        const int j0 = (r & 3) * 128;

        {   // stage za strip: thread -> (p = tid>>2, ii = (tid&3)*4)
            const int p  = tid >> 2;
            const int i4 = (tid & 3) * 4;
            *(float4*)(zas + p * 16 + i4) =
                *(const float4*)(zat + (size_t)(b * P_ + p) * 512 + i0 + i4);
        }
        __syncthreads();

        const int rr = tid >> 7;             // row-half: rows rr*8 .. rr*8+7
        const int j  = j0 + (tid & 127);

        float acc[8];
        #pragma unroll
        for (int u = 0; u < 8; ++u) acc[u] = 0.f;

        for (int p = 0; p < P_; ++p) {
            const float zb = zbt[(size_t)(b * P_ + p) * 512 + j];
            #pragma unroll
            for (int u = 0; u < 8; ++u)
                acc[u] = fmaf(zas[p * 16 + rr * 8 + u], zb, acc[u]);
        }

        const float rbj = rnb[b * 512 + j];
        float* plane = out + (size_t)(b * NCH_ + 256) * CH_;
        #pragma unroll
        for (int u = 0; u < 8; ++u) {
            const int i = i0 + rr * 8 + u;
            plane[(size_t)i * LB_ + j] = acc[u] * rna[b * 512 + i] * rbj;
        }
    }
}

// ---------------------------------------------------------------------------
extern "C" void kernel_launch(void* const* d_in, const int* in_sizes, int n_in,
                              void* d_out, int out_size, void* d_ws, size_t ws_size,
                              hipStream_t stream)
{
    const float* h_a = (const float*)d_in[0];
    const float* h_b = (const float*)d_in[1];
    const float* Wa  = (const float*)d_in[2];
    const float* ba  = (const float*)d_in[3];
    const float* Wb  = (const float*)d_in[4];
    const float* bb  = (const float*)d_in[5];
    float* out = (float*)d_out;

    // workspace (floats): zat[65536] | zbt[65536] | rna[1024] | rnb[1024]
    float* ws  = (float*)d_ws;
    float* zat = ws;
    float* zbt = zat + (size_t)B_ * P_ * LA_;
    float* rna = zbt + (size_t)B_ * P_ * LB_;
    float* rnb = rna + (size_t)B_ * LA_;

    proj_gelu_kernel<<<2 * B_ * LA_, 256, 0, stream>>>(
        h_a, Wa, ba, h_b, Wb, bb, zat, zbt, rna, rnb);
    map_kernel<<<dim3(SIMBLK_ + WBLK_), 256, 0, stream>>>(
        zat, zbt, rna, rnb, out);
}